// Round 1
// baseline (335.191 us; speedup 1.0000x reference)
//
#include <hip/hip_runtime.h>
#include <math.h>

// Bahdanau attention, B=32, T=2048, D=512, U=512, fp32 in/out.
// Round 8: fix prep_fused cvt coalescing. Old pattern gave each thread a
// contiguous 64B chunk -> per-instruction lanes strided 64B -> each 64B
// sector requested by 4 instructions (4x request amplification, 1.5 TB/s).
// New pattern: lane-contiguous float4 loads (1KB/wave/instr) + half4 8B
// stores (512B/wave/instr), zero amplification.

#define B_ 32
#define T_ 2048
#define D_ 512
#define U_ 512
#define M_ (B_ * T_)

typedef _Float16 half8 __attribute__((ext_vector_type(8)));
typedef _Float16 half4 __attribute__((ext_vector_type(4)));
typedef float floatx4 __attribute__((ext_vector_type(4)));

__device__ __forceinline__ float fast_tanh(float x) {
  x = fminf(fmaxf(x, -20.f), 20.f);
  const float e = __expf(2.f * x);
  return 1.f - 2.f / (e + 1.f);
}

__device__ __forceinline__ void load_lds16(const _Float16* g, _Float16* l) {
  __builtin_amdgcn_global_load_lds(
      (const __attribute__((address_space(1))) void*)g,
      (__attribute__((address_space(3))) void*)l, 16, 0, 0);
}

// ---------------- prep: cvt values->f16 | W1->w1t | projq | zero outs ------
// blocks [0,8192): values fp32 -> valf16 (skipped if do_cvt==0)
// blocks [8192,8256): W1 [k][u] -> w1t [u][k] f16 (64 x 64x64 tiles)
// blocks [8256,8320): projq = query@W2+b2; zero context + scores
__global__ __launch_bounds__(256) void prep_fused(
    const float* __restrict__ values, const float* __restrict__ W1,
    const float* __restrict__ query, const float* __restrict__ W2,
    const float* __restrict__ b2, _Float16* __restrict__ valf16,
    _Float16* __restrict__ w1t, float* __restrict__ projq,
    float* __restrict__ scores, float* __restrict__ context, int do_cvt) {
  __shared__ float sh[64 * 65];
  const int bx = blockIdx.x;
  const int tid = threadIdx.x;
  if (bx < 8192) {
    if (!do_cvt) return;
    // 4096 floats per block; every load/store instruction lane-contiguous.
    const long base = (long)bx * 4096;
#pragma unroll
    for (int j = 0; j < 4; ++j) {
      const long idx = base + j * 1024 + tid * 4;
      const float4 a = *(const float4*)(values + idx);
      half4 h = {(_Float16)a.x, (_Float16)a.y, (_Float16)a.z, (_Float16)a.w};
      *(half4*)(valf16 + idx) = h;
    }
  } else if (bx < 8256) {
    const int t = bx - 8192;
    const int k0 = (t >> 3) * 64, u0 = (t & 7) * 64;
    float(*sm)[65] = (float(*)[65])sh;
    const int lu = tid & 63;
    const int g = tid >> 6;
#pragma unroll
    for (int i = 0; i < 16; ++i) {
      const int row = g * 16 + i;
      sm[row][lu] = W1[(long)(k0 + row) * U_ + u0 + lu];
    }
    __syncthreads();
#pragma unroll
    for (int i = 0; i < 16; ++i) {
      const int row = g * 16 + i;
      w1t[(long)(u0 + row) * D_ + k0 + lu] = (_Float16)sm[lu][row];
    }
  } else {
    const int t = bx - 8256;  // [0,64)
    const int gid = t * 256 + tid;
    context[gid] = 0.f;                                     // 16384 floats
    ((float4*)scores)[gid] = make_float4(0.f, 0.f, 0.f, 0.f);  // 65536 floats
    const int b = t >> 1;
    const int u = (t & 1) * 256 + tid;
    for (int d = tid; d < D_; d += 256) sh[d] = query[b * D_ + d];
    __syncthreads();
    float acc = 0.f;
#pragma unroll 8
    for (int d = 0; d < D_; ++d) acc += sh[d] * W2[d * U_ + u];
    projq[b * U_ + u] = acc + b2[u];
  }
}

// ---------------- scores: DMA-staged f16 MFMA, 256x128 tile ----------------
// Grid (M/256, U/128). 256 threads = 4 waves 2x2; wave = 128m x 64u via
// 8x4 grid of 16x16x32 MFMA (acc 128 regs; launch_bounds(256,2)).
// A: valf16 -> LDS via global_load_lds, rows 32 f16 = 64B = 4 chunks of 16B,
// global chunk c of row r stored at slot c^(r&3) -> frag reads spread banks.
// B: direct global half8 from w1t [u][k] (L2-resident).
// Frag layouts (verified r2-r6): A[m=lane&15][k=(lane>>4)*8+j],
// B[k=(lane>>4)*8+j][n=lane&15], C[row=(lane>>4)*4+reg][col=lane&15].
__global__ __launch_bounds__(256, 2) void score_dma_kernel(
    const _Float16* __restrict__ valf16, const _Float16* __restrict__ w1t,
    const float* __restrict__ b1, const float* __restrict__ projq,
    const float* __restrict__ V, float* __restrict__ scores) {
  const int m0 = blockIdx.x * 256;
  const int b = blockIdx.x >> 3;  // 2048/256 = 8 row-blocks per batch
  const int u0 = blockIdx.y * 128;
  const int tid = threadIdx.x;
  const int lane = tid & 63;
  const int w = tid >> 6;
  const int wm = (w & 1) * 128;
  const int wn = u0 + (w >> 1) * 64;
  const int ln = lane & 15;
  const int lq = lane >> 4;

  __shared__ alignas(16) _Float16 As[256 * 32];  // [m][32k] packed, swizzled
  __shared__ float red[2][256];

  // DMA: wave w stages rows [w*64, w*64+64) in 4 groups of 16 rows.
  const int rl = lane >> 2;                       // 0..15 within group
  const int cg = (lane & 3) ^ (rl & 3);           // swizzled global chunk
  const _Float16* gA[4];
  _Float16* lA[4];
#pragma unroll
  for (int j = 0; j < 4; ++j) {
    const int r = w * 64 + j * 16 + rl;
    gA[j] = valf16 + (long)(m0 + r) * D_ + cg * 8;
    lA[j] = &As[(w * 64 + j * 16) * 32];
  }

  const _Float16* bp[4];
#pragma unroll
  for (int ni = 0; ni < 4; ++ni)
    bp[ni] = w1t + (long)(wn + ni * 16 + ln) * D_ + lq * 8;

  const int aswz = (lq ^ (ln & 3)) * 8;  // swizzled frag k-slot

  floatx4 acc[8][4] = {};

  for (int k0 = 0; k0 < D_; k0 += 32) {
#pragma unroll
    for (int j = 0; j < 4; ++j) load_lds16(gA[j] + k0, lA[j]);
    half8 bf[4];
#pragma unroll
    for (int ni = 0; ni < 4; ++ni) bf[ni] = *(const half8*)(bp[ni] + k0);
    __syncthreads();  // drains DMA + bf loads
    half8 af[8];
#pragma unroll
    for (int mi = 0; mi < 8; ++mi)
      af[mi] = *(const half8*)&As[(wm + mi * 16 + ln) * 32 + aswz];
#pragma unroll
    for (int mi = 0; mi < 8; ++mi)
#pragma unroll
      for (int ni = 0; ni < 4; ++ni)
        acc[mi][ni] = __builtin_amdgcn_mfma_f32_16x16x32_f16(
            af[mi], bf[ni], acc[mi][ni], 0, 0, 0);
    __syncthreads();  // LDS consumed before next DMA overwrites
  }

  // Epilogue: row partials of tanh(c + b1 + projq) * V over this wave's 64 u
  float pre[4], vv[4];
#pragma unroll
  for (int ni = 0; ni < 4; ++ni) {
    const int u = wn + ni * 16 + ln;
    pre[ni] = b1[u] + projq[b * U_ + u];
    vv[ni] = V[u];
  }
#pragma unroll
  for (int mi = 0; mi < 8; ++mi) {
#pragma unroll
    for (int r = 0; r < 4; ++r) {
      float t = 0.f;
#pragma unroll
      for (int ni = 0; ni < 4; ++ni)
        t += fast_tanh(acc[mi][ni][r] + pre[ni]) * vv[ni];
      t += __shfl_xor(t, 1);
      t += __shfl_xor(t, 2);
      t += __shfl_xor(t, 4);
      t += __shfl_xor(t, 8);
      if (ln == 0) red[w >> 1][wm + mi * 16 + lq * 4 + r] = t;
    }
  }
  __syncthreads();
  atomicAdd(scores + m0 + tid, red[0][tid] + red[1][tid]);
}

// ---------------- fallback score (r4 structure) if ws < 68MB ---------------
__global__ __launch_bounds__(256) void score_lds_kernel(
    const float* __restrict__ values, const _Float16* __restrict__ w1t,
    const float* __restrict__ b1, const float* __restrict__ projq,
    const float* __restrict__ V, float* __restrict__ scores) {
  const int m0 = blockIdx.x * 128;
  const int u0 = blockIdx.y * 128;
  const int b = blockIdx.x >> 4;
  const int tid = threadIdx.x;
  const int lane = tid & 63;
  const int w = tid >> 6;
  const int wm = (w & 1) * 64;
  const int wn = (w >> 1) * 64;
  const int ln = lane & 15;
  const int lq = lane >> 4;
  __shared__ alignas(16) _Float16 As[128 * 40];
  const int srow = tid >> 1;
  const int skoff = (tid & 1) * 16;
  const float* aptr = values + (long)(m0 + srow) * D_ + skoff;
  _Float16* awr = &As[srow * 40 + skoff];
  const _Float16* bBase = w1t + (long)(u0 + wn + ln) * D_ + lq * 8;
  floatx4 acc[4][4] = {};
  for (int k0 = 0; k0 < D_; k0 += 32) {
    const float4 a0 = *(const float4*)(aptr + k0);
    const float4 a1 = *(const float4*)(aptr + k0 + 4);
    const float4 a2 = *(const float4*)(aptr + k0 + 8);
    const float4 a3 = *(const float4*)(aptr + k0 + 12);
    half8 bf[4];
#pragma unroll
    for (int ni = 0; ni < 4; ++ni)
      bf[ni] = *(const half8*)(bBase + (long)ni * 16 * D_ + k0);
    half8 h0 = {(_Float16)a0.x, (_Float16)a0.y, (_Float16)a0.z, (_Float16)a0.w,
                (_Float16)a1.x, (_Float16)a1.y, (_Float16)a1.z, (_Float16)a1.w};
    half8 h1 = {(_Float16)a2.x, (_Float16)a2.y, (_Float16)a2.z, (_Float16)a2.w,
                (_Float16)a3.x, (_Float16)a3.y, (_Float16)a3.z, (_Float16)a3.w};
    *(half8*)awr = h0;
    *(half8*)(awr + 8) = h1;
    __syncthreads();
    half8 af[4];
#pragma unroll
    for (int i = 0; i < 4; ++i)
      af[i] = *(const half8*)&As[(wm + i * 16 + ln) * 40 + lq * 8];
#pragma unroll
    for (int mi = 0; mi < 4; ++mi)
#pragma unroll
      for (int ni = 0; ni < 4; ++ni)
        acc[mi][ni] = __builtin_amdgcn_mfma_f32_16x16x32_f16(
            af[mi], bf[ni], acc[mi][ni], 0, 0, 0);
    __syncthreads();
  }
  float pre[4], vv[4];
#pragma unroll
  for (int ni = 0; ni < 4; ++ni) {
    const int u = u0 + wn + ni * 16 + ln;
    pre[ni] = b1[u] + projq[b * U_ + u];
    vv[ni] = V[u];
  }
#pragma unroll
  for (int mi = 0; mi < 4; ++mi) {
#pragma unroll
    for (int r = 0; r < 4; ++r) {
      float t = 0.f;
#pragma unroll
      for (int ni = 0; ni < 4; ++ni)
        t += fast_tanh(acc[mi][ni][r] + pre[ni]) * vv[ni];
      t += __shfl_xor(t, 1);
      t += __shfl_xor(t, 2);
      t += __shfl_xor(t, 4);
      t += __shfl_xor(t, 8);
      if (ln == mi * 4 + r)
        atomicAdd(scores + m0 + wm + mi * 16 + lq * 4 + r, t);
    }
  }
}

// ---------------- fused softmax + context ----------------
// Grid (B, T/64). Every block recomputes batch-b softmax stats from scores
// (deterministic -> consistent across blocks), writes its 64-row weight
// slice, accumulates its context partial via atomics.
__global__ __launch_bounds__(256) void softmax_context_kernel(
    const float* __restrict__ scores, const float* __restrict__ values,
    float* __restrict__ weights, float* __restrict__ context) {
  const int b = blockIdx.x;
  const int t0 = blockIdx.y * 64;
  const int tid = threadIdx.x;

  // full-batch softmax stats
  float v[8];
  float mx = -INFINITY;
#pragma unroll
  for (int i = 0; i < 8; ++i) {
    v[i] = scores[b * T_ + i * 256 + tid];
    mx = fmaxf(mx, v[i]);
  }
#pragma unroll
  for (int off = 32; off > 0; off >>= 1) mx = fmaxf(mx, __shfl_down(mx, off));
  __shared__ float sm[4], ss[4];
  if ((tid & 63) == 0) sm[tid >> 6] = mx;
  __syncthreads();
  mx = fmaxf(fmaxf(sm[0], sm[1]), fmaxf(sm[2], sm[3]));
  float sum = 0.f;
#pragma unroll
  for (int i = 0; i < 8; ++i) sum += __expf(v[i] - mx);
#pragma unroll
  for (int off = 32; off > 0; off >>= 1) sum += __shfl_down(sum, off);
  if ((tid & 63) == 0) ss[tid >> 6] = sum;
  __syncthreads();
  const float inv = 1.f / (ss[0] + ss[1] + ss[2] + ss[3]);

  // weights for our 64 rows
  __shared__ float wsh[64];
  if (tid < 64) {
    const float ww = __expf(scores[b * T_ + t0 + tid] - mx) * inv;
    wsh[tid] = ww;
    weights[b * T_ + t0 + tid] = ww;
  }
  __syncthreads();

  // context partial
  const int g = tid >> 7;
  const int dx = tid & 127;
  __shared__ float4 part[128];
  float4 acc = make_float4(0.f, 0.f, 0.f, 0.f);
  const float4* vp = (const float4*)(values + (long)(b * T_ + t0 + g) * D_) + dx;
#pragma unroll 4
  for (int t = 0; t < 32; ++t) {
    const float4 x = vp[(long)(2 * t) * (D_ / 4)];
    const float ww = wsh[2 * t + g];
    acc.x += ww * x.x; acc.y += ww * x.y; acc.z += ww * x.z; acc.w += ww * x.w;
  }
  if (g == 0) part[dx] = acc;
  __syncthreads();
  if (g == 1) {
    const float4 p = part[dx];
    atomicAdd(&context[b * D_ + dx * 4 + 0], acc.x + p.x);
    atomicAdd(&context[b * D_ + dx * 4 + 1], acc.y + p.y);
    atomicAdd(&context[b * D_ + dx * 4 + 2], acc.z + p.z);
    atomicAdd(&context[b * D_ + dx * 4 + 3], acc.w + p.w);
  }
}

extern "C" void kernel_launch(void* const* d_in, const int* in_sizes, int n_in,
                              void* d_out, int out_size, void* d_ws, size_t ws_size,
                              hipStream_t stream) {
  const float* values = (const float*)d_in[0];
  const float* query = (const float*)d_in[1];
  const float* W1 = (const float*)d_in[2];
  const float* b1 = (const float*)d_in[3];
  const float* W2 = (const float*)d_in[4];
  const float* b2 = (const float*)d_in[5];
  const float* V = (const float*)d_in[6];
  // d_in[7] = bV: unused — softmax is shift-invariant.

  float* out = (float*)d_out;
  float* context = out;            // [32,512]
  float* weights = out + B_ * D_;  // [32,2048]
  float* projq = (float*)d_ws;                                // 64KB
  float* scores = projq + B_ * U_;                            // 256KB
  _Float16* w1t = (_Float16*)((char*)d_ws + 65536 + 262144);  // 512KB
  _Float16* valf16 = (_Float16*)((char*)d_ws + 851968);       // 64MB

  const int dma = ws_size >= (size_t)851968 + (size_t)M_ * D_ * 2;

  prep_fused<<<8320, 256, 0, stream>>>(values, W1, query, W2, b2, valf16, w1t,
                                       projq, scores, context, dma);
  if (dma) {
    score_dma_kernel<<<dim3(M_ / 256, U_ / 128), 256, 0, stream>>>(
        valf16, w1t, b1, projq, V, scores);
  } else {
    score_lds_kernel<<<dim3(M_ / 128, U_ / 128), 256, 0, stream>>>(
        values, w1t, b1, projq, V, scores);
  }
  softmax_context_kernel<<<dim3(B_, T_ / 64), 256, 0, stream>>>(
      scores, values, weights, context);
}

// Round 2
// 318.878 us; speedup vs baseline: 1.0512x; 1.0512x over previous
//
#include <hip/hip_runtime.h>
#include <math.h>

// Bahdanau attention, B=32, T=2048, D=512, U=512, fp32 in/out.
// Round 9: eliminate the 91us cvt pass entirely. score_fused reads values
// fp32 directly (DMA to LDS via global_load_lds with source-side XOR chunk
// swizzle), converts to f16 in-register at fragment-load time. Each block
// covers the FULL U=512 for a 128-row m-tile -> values read exactly once,
// scores complete per block (no atomics, no zeroing). prep shrinks to
// W1-transpose + projq + context-zero (128 small blocks).

#define B_ 32
#define T_ 2048
#define D_ 512
#define U_ 512
#define M_ (B_ * T_)

typedef _Float16 half8 __attribute__((ext_vector_type(8)));
typedef float floatx4 __attribute__((ext_vector_type(4)));

__device__ __forceinline__ float fast_tanh(float x) {
  x = fminf(fmaxf(x, -20.f), 20.f);
  const float e = __expf(2.f * x);
  return 1.f - 2.f / (e + 1.f);
}

__device__ __forceinline__ void load_lds16f(const float* g, float* l) {
  __builtin_amdgcn_global_load_lds(
      (const __attribute__((address_space(1))) void*)g,
      (__attribute__((address_space(3))) void*)l, 16, 0, 0);
}

// ---------------- prep: W1->w1t | projq | zero context ---------------------
// blocks [0,64): W1 [k][u] -> w1t [u][k] f16 (64 x 64x64 tiles)
// blocks [64,128): projq = query@W2+b2; zero context
__global__ __launch_bounds__(256) void prep_fused(
    const float* __restrict__ W1, const float* __restrict__ query,
    const float* __restrict__ W2, const float* __restrict__ b2,
    _Float16* __restrict__ w1t, float* __restrict__ projq,
    float* __restrict__ context) {
  __shared__ float sh[64 * 65];
  const int bx = blockIdx.x;
  const int tid = threadIdx.x;
  if (bx < 64) {
    const int t = bx;
    const int k0 = (t >> 3) * 64, u0 = (t & 7) * 64;
    float(*sm)[65] = (float(*)[65])sh;
    const int lu = tid & 63;
    const int g = tid >> 6;
#pragma unroll
    for (int i = 0; i < 16; ++i) {
      const int row = g * 16 + i;
      sm[row][lu] = W1[(long)(k0 + row) * U_ + u0 + lu];
    }
    __syncthreads();
#pragma unroll
    for (int i = 0; i < 16; ++i) {
      const int row = g * 16 + i;
      w1t[(long)(u0 + row) * D_ + k0 + lu] = (_Float16)sm[lu][row];
    }
  } else {
    const int t = bx - 64;  // [0,64)
    const int gid = t * 256 + tid;
    context[gid] = 0.f;  // 16384 floats
    const int b = t >> 1;
    const int u = (t & 1) * 256 + tid;
    for (int d = tid; d < D_; d += 256) sh[d] = query[b * D_ + d];
    __syncthreads();
    float acc = 0.f;
#pragma unroll 8
    for (int d = 0; d < D_; ++d) acc += sh[d] * W2[d * U_ + u];
    projq[b * U_ + u] = acc + b2[u];
  }
}

// ---------------- scores: fused fp32-read MFMA, 128m x 512u per block ------
// Grid M/128 = 512 blocks, 512 threads = 8 waves (2m x 4u).
// Wave = 64m x 128u via 4x8 grid of 16x16x32 MFMA (acc 128 VGPR).
// A: values fp32 -> LDS [128][32] f32 via global_load_lds, double-buffered.
//    Row = 8 chunks of 16B; chunk stored at slot s holds global chunk
//    s^(row&7) (source-side swizzle -> conflict-free b128 frag reads).
// Fragments: read 2x float4 from LDS, cvt to half8 in-register (RTE).
// B: direct global half8 from w1t [u][k] (512KB, L2-resident).
// Frag layouts (verified r2-r6): A[m=lane&15][k=(lane>>4)*8+j],
// B[k=(lane>>4)*8+j][n=lane&15], C[row=(lane>>4)*4+reg][col=lane&15].
// DMA for step t+1 issued AFTER bf loads of step t: compiler's pre-MFMA
// wait is then vmcnt(2) (DMAs stay in flight through the MFMA phase),
// drained only at the single per-step barrier.
__global__ __launch_bounds__(512, 1) void score_fused(
    const float* __restrict__ values, const _Float16* __restrict__ w1t,
    const float* __restrict__ b1, const float* __restrict__ projq,
    const float* __restrict__ V, float* __restrict__ scores) {
  const int m0 = blockIdx.x * 128;
  const int b = blockIdx.x >> 4;  // 2048/128 = 16 row-blocks per batch
  const int tid = threadIdx.x;
  const int lane = tid & 63;
  const int w = tid >> 6;          // 0..7
  const int wm = (w & 1) * 64;     // m-half
  const int wu = (w >> 1) * 128;   // u-quarter
  const int ln = lane & 15;
  const int lq = lane >> 4;

  __shared__ alignas(16) float As[2][128 * 32];  // 32 KB, double-buffered
  __shared__ float red[4][128];                  // 2 KB

  // DMA: wave w stages rows [16w,16w+16) per k-step, 2 instrs of 8 rows.
  // lane l -> row R+(l>>3), LDS slot l&7; source chunk = (l&7)^(l>>3)
  // (row&7 == l>>3 since R%8==0).
  const int dr = lane >> 3;
  const int dc = (lane & 7) ^ dr;
  const float* gA[2];
#pragma unroll
  for (int j = 0; j < 2; ++j) {
    const int r = w * 16 + j * 8 + dr;
    gA[j] = values + (long)(m0 + r) * D_ + dc * 4;
  }

  const _Float16* bp[8];
#pragma unroll
  for (int ni = 0; ni < 8; ++ni)
    bp[ni] = w1t + (long)(wu + ni * 16 + ln) * D_ + lq * 8;

  floatx4 acc[4][8] = {};

  // prologue: stage k-step 0 into buf 0
#pragma unroll
  for (int j = 0; j < 2; ++j)
    load_lds16f(gA[j], &As[0][(w * 16 + j * 8) * 32]);
  __syncthreads();

  for (int t = 0; t < 16; ++t) {
    const int p = t & 1;
    // B fragments for this step (issued BEFORE next-step DMA).
    half8 bf[8];
#pragma unroll
    for (int ni = 0; ni < 8; ++ni) bf[ni] = *(const half8*)(bp[ni] + t * 32);
    // next-step DMA into the other buffer (in flight through MFMA phase)
    if (t < 15) {
#pragma unroll
      for (int j = 0; j < 2; ++j)
        load_lds16f(gA[j] + (t + 1) * 32,
                    &As[p ^ 1][(w * 16 + j * 8) * 32]);
    }
    // A fragments: 2x ds_read_b128 + cvt to half8
    half8 af[4];
#pragma unroll
    for (int mi = 0; mi < 4; ++mi) {
      const int r = wm + mi * 16 + ln;
      const float* row = &As[p][r * 32];
      const float4 lo = *(const float4*)(row + (((2 * lq) ^ (r & 7)) * 4));
      const float4 hi = *(const float4*)(row + (((2 * lq + 1) ^ (r & 7)) * 4));
      af[mi] = half8{(_Float16)lo.x, (_Float16)lo.y, (_Float16)lo.z,
                     (_Float16)lo.w, (_Float16)hi.x, (_Float16)hi.y,
                     (_Float16)hi.z, (_Float16)hi.w};
    }
#pragma unroll
    for (int mi = 0; mi < 4; ++mi)
#pragma unroll
      for (int ni = 0; ni < 8; ++ni)
        acc[mi][ni] = __builtin_amdgcn_mfma_f32_16x16x32_f16(
            af[mi], bf[ni], acc[mi][ni], 0, 0, 0);
    __syncthreads();  // buf[p] consumed; drains DMA(t+1) into buf[p^1]
  }

  // Epilogue: full row scores (each block owns its 128 rows exclusively).
  float pre[8], vv[8];
#pragma unroll
  for (int ni = 0; ni < 8; ++ni) {
    const int u = wu + ni * 16 + ln;
    pre[ni] = b1[u] + projq[b * U_ + u];
    vv[ni] = V[u];
  }
#pragma unroll
  for (int mi = 0; mi < 4; ++mi) {
#pragma unroll
    for (int r = 0; r < 4; ++r) {
      float t = 0.f;
#pragma unroll
      for (int ni = 0; ni < 8; ++ni)
        t += fast_tanh(acc[mi][ni][r] + pre[ni]) * vv[ni];
      t += __shfl_xor(t, 1);
      t += __shfl_xor(t, 2);
      t += __shfl_xor(t, 4);
      t += __shfl_xor(t, 8);
      if (ln == 0) red[w >> 1][wm + mi * 16 + lq * 4 + r] = t;
    }
  }
  __syncthreads();
  if (tid < 128)
    scores[m0 + tid] =
        red[0][tid] + red[1][tid] + red[2][tid] + red[3][tid];
}

// ---------------- fused softmax + context ----------------
// Grid (B, T/64). Every block recomputes batch-b softmax stats from scores
// (deterministic -> consistent across blocks), writes its 64-row weight
// slice, accumulates its context partial via atomics.
__global__ __launch_bounds__(256) void softmax_context_kernel(
    const float* __restrict__ scores, const float* __restrict__ values,
    float* __restrict__ weights, float* __restrict__ context) {
  const int b = blockIdx.x;
  const int t0 = blockIdx.y * 64;
  const int tid = threadIdx.x;

  // full-batch softmax stats
  float v[8];
  float mx = -INFINITY;
#pragma unroll
  for (int i = 0; i < 8; ++i) {
    v[i] = scores[b * T_ + i * 256 + tid];
    mx = fmaxf(mx, v[i]);
  }
#pragma unroll
  for (int off = 32; off > 0; off >>= 1) mx = fmaxf(mx, __shfl_down(mx, off));
  __shared__ float sm[4], ss[4];
  if ((tid & 63) == 0) sm[tid >> 6] = mx;
  __syncthreads();
  mx = fmaxf(fmaxf(sm[0], sm[1]), fmaxf(sm[2], sm[3]));
  float sum = 0.f;
#pragma unroll
  for (int i = 0; i < 8; ++i) sum += __expf(v[i] - mx);
#pragma unroll
  for (int off = 32; off > 0; off >>= 1) sum += __shfl_down(sum, off);
  if ((tid & 63) == 0) ss[tid >> 6] = sum;
  __syncthreads();
  const float inv = 1.f / (ss[0] + ss[1] + ss[2] + ss[3]);

  // weights for our 64 rows
  __shared__ float wsh[64];
  if (tid < 64) {
    const float ww = __expf(scores[b * T_ + t0 + tid] - mx) * inv;
    wsh[tid] = ww;
    weights[b * T_ + t0 + tid] = ww;
  }
  __syncthreads();

  // context partial
  const int g = tid >> 7;
  const int dx = tid & 127;
  __shared__ float4 part[128];
  float4 acc = make_float4(0.f, 0.f, 0.f, 0.f);
  const float4* vp = (const float4*)(values + (long)(b * T_ + t0 + g) * D_) + dx;
#pragma unroll 4
  for (int t = 0; t < 32; ++t) {
    const float4 x = vp[(long)(2 * t) * (D_ / 4)];
    const float ww = wsh[2 * t + g];
    acc.x += ww * x.x; acc.y += ww * x.y; acc.z += ww * x.z; acc.w += ww * x.w;
  }
  if (g == 0) part[dx] = acc;
  __syncthreads();
  if (g == 1) {
    const float4 p = part[dx];
    atomicAdd(&context[b * D_ + dx * 4 + 0], acc.x + p.x);
    atomicAdd(&context[b * D_ + dx * 4 + 1], acc.y + p.y);
    atomicAdd(&context[b * D_ + dx * 4 + 2], acc.z + p.z);
    atomicAdd(&context[b * D_ + dx * 4 + 3], acc.w + p.w);
  }
}

extern "C" void kernel_launch(void* const* d_in, const int* in_sizes, int n_in,
                              void* d_out, int out_size, void* d_ws, size_t ws_size,
                              hipStream_t stream) {
  const float* values = (const float*)d_in[0];
  const float* query = (const float*)d_in[1];
  const float* W1 = (const float*)d_in[2];
  const float* b1 = (const float*)d_in[3];
  const float* W2 = (const float*)d_in[4];
  const float* b2 = (const float*)d_in[5];
  const float* V = (const float*)d_in[6];
  // d_in[7] = bV: unused — softmax is shift-invariant.

  float* out = (float*)d_out;
  float* context = out;            // [32,512]
  float* weights = out + B_ * D_;  // [32,2048]
  float* projq = (float*)d_ws;                                // 64KB
  float* scores = projq + B_ * U_;                            // 256KB
  _Float16* w1t = (_Float16*)((char*)d_ws + 65536 + 262144);  // 512KB

  prep_fused<<<128, 256, 0, stream>>>(W1, query, W2, b2, w1t, projq, context);
  score_fused<<<M_ / 128, 512, 0, stream>>>(values, w1t, b1, projq, V, scores);
  softmax_context_kernel<<<dim3(B_, T_ / 64), 256, 0, stream>>>(
      scores, values, weights, context);
}

// Round 3
// 298.419 us; speedup vs baseline: 1.1232x; 1.0686x over previous
//
#include <hip/hip_runtime.h>
#include <math.h>

// Bahdanau attention, B=32, T=2048, D=512, U=512, fp32 in/out.
// Round 10: B (w1t) staged through LDS double-buffer alongside A instead of
// per-step global fragment loads. r9's 8 global B-loads/step were exposed
// L3/HBM latency every step (values streaming evicts w1t from the 4MB XCD
// L2), giving ~8400cyc/step. Now the steady-state loop touches global only
// via prefetch DMAs (A 16KB + B 32KB per step) drained at the existing
// barrier; all fragment reads are LDS. LDS = 32(A) + 64(B) + 2(red) = 98KB.

#define B_ 32
#define T_ 2048
#define D_ 512
#define U_ 512
#define M_ (B_ * T_)

typedef _Float16 half8 __attribute__((ext_vector_type(8)));
typedef float floatx4 __attribute__((ext_vector_type(4)));

__device__ __forceinline__ float fast_tanh(float x) {
  x = fminf(fmaxf(x, -20.f), 20.f);
  const float e = __expf(2.f * x);
  return 1.f - 2.f / (e + 1.f);
}

__device__ __forceinline__ void load_lds16f(const float* g, float* l) {
  __builtin_amdgcn_global_load_lds(
      (const __attribute__((address_space(1))) void*)g,
      (__attribute__((address_space(3))) void*)l, 16, 0, 0);
}

__device__ __forceinline__ void load_lds16h(const _Float16* g, _Float16* l) {
  __builtin_amdgcn_global_load_lds(
      (const __attribute__((address_space(1))) void*)g,
      (__attribute__((address_space(3))) void*)l, 16, 0, 0);
}

// ---------------- prep: W1->w1t | projq | zero context ---------------------
// blocks [0,64): W1 [k][u] -> w1t [u][k] f16 (64 x 64x64 tiles)
// blocks [64,128): projq = query@W2+b2; zero context
__global__ __launch_bounds__(256) void prep_fused(
    const float* __restrict__ W1, const float* __restrict__ query,
    const float* __restrict__ W2, const float* __restrict__ b2,
    _Float16* __restrict__ w1t, float* __restrict__ projq,
    float* __restrict__ context) {
  __shared__ float sh[64 * 65];
  const int bx = blockIdx.x;
  const int tid = threadIdx.x;
  if (bx < 64) {
    const int t = bx;
    const int k0 = (t >> 3) * 64, u0 = (t & 7) * 64;
    float(*sm)[65] = (float(*)[65])sh;
    const int lu = tid & 63;
    const int g = tid >> 6;
#pragma unroll
    for (int i = 0; i < 16; ++i) {
      const int row = g * 16 + i;
      sm[row][lu] = W1[(long)(k0 + row) * U_ + u0 + lu];
    }
    __syncthreads();
#pragma unroll
    for (int i = 0; i < 16; ++i) {
      const int row = g * 16 + i;
      w1t[(long)(u0 + row) * D_ + k0 + lu] = (_Float16)sm[lu][row];
    }
  } else {
    const int t = bx - 64;  // [0,64)
    const int gid = t * 256 + tid;
    context[gid] = 0.f;  // 16384 floats
    const int b = t >> 1;
    const int u = (t & 1) * 256 + tid;
    for (int d = tid; d < D_; d += 256) sh[d] = query[b * D_ + d];
    __syncthreads();
    float acc = 0.f;
#pragma unroll 8
    for (int d = 0; d < D_; ++d) acc += sh[d] * W2[d * U_ + u];
    projq[b * U_ + u] = acc + b2[u];
  }
}

// ---------------- scores: fused fp32-read MFMA, 128m x 512u per block ------
// Grid M/128 = 512 blocks, 512 threads = 8 waves (2m x 4u).
// Wave = 64m x 128u via 4x8 grid of 16x16x32 MFMA (acc 128 regs).
// A: values fp32 -> LDS [128][32] f32 via global_load_lds, double-buffered,
//    source-side XOR chunk swizzle (slot s of row r holds chunk s^(r&7)).
//    Fragments read as 2x float4 + in-register cvt to half8 (RTE).
// B: w1t [u][k] f16 -> LDS [512][32] halves via global_load_lds, double-
//    buffered, source-side swizzle (slot s of row r holds chunk s^(r&3),
//    rows are 32 halves = 4x16B chunks).
// Frag layouts (verified r2-r6): A[m=lane&15][k=(lane>>4)*8+j],
// B[k=(lane>>4)*8+j][n=lane&15], C[row=(lane>>4)*4+reg][col=lane&15].
// Steady state: step t issues DMA(t+1) for both A and B, reads its frags
// from LDS, runs 32 MFMA, barrier (drains DMA). No global loads in-loop.
__global__ __launch_bounds__(512, 1) void score_fused(
    const float* __restrict__ values, const _Float16* __restrict__ w1t,
    const float* __restrict__ b1, const float* __restrict__ projq,
    const float* __restrict__ V, float* __restrict__ scores) {
  const int m0 = blockIdx.x * 128;
  const int b = blockIdx.x >> 4;  // 2048/128 = 16 row-blocks per batch
  const int tid = threadIdx.x;
  const int lane = tid & 63;
  const int w = tid >> 6;          // 0..7
  const int wm = (w & 1) * 64;     // m-half
  const int wu = (w >> 1) * 128;   // u-quarter
  const int ln = lane & 15;
  const int lq = lane >> 4;

  __shared__ alignas(16) float As[2][128 * 32];     // 32 KB dbuf
  __shared__ alignas(16) _Float16 Bs[2][512 * 32];  // 64 KB dbuf
  __shared__ float red[4][128];                     // 2 KB

  // A-DMA: wave w stages rows [16w,16w+16) per step, 2 instrs of 8 rows.
  // lane l -> row +(l>>3), slot l&7; source chunk (l&7)^(l>>3).
  const int dr = lane >> 3;
  const int dc = (lane & 7) ^ dr;
  const float* gA[2];
#pragma unroll
  for (int j = 0; j < 2; ++j) {
    const int r = w * 16 + j * 8 + dr;
    gA[j] = values + (long)(m0 + r) * D_ + dc * 4;
  }

  // B-DMA: wave w stages rows [64w,64w+64) per step, 4 instrs of 16 rows.
  // Row = 32 halves = 4 chunks of 16B. lane l -> row +(l>>2), slot l&3;
  // source chunk (l&3)^((l>>2)&3).
  const int br = lane >> 2;
  const int bc = (lane & 3) ^ (br & 3);
  const _Float16* gB[4];
#pragma unroll
  for (int i = 0; i < 4; ++i) {
    const int r = w * 64 + i * 16 + br;
    gB[i] = w1t + (long)r * D_ + bc * 8;
  }

  floatx4 acc[4][8] = {};

  // prologue: stage k-step 0 into buf 0
#pragma unroll
  for (int j = 0; j < 2; ++j)
    load_lds16f(gA[j], &As[0][(w * 16 + j * 8) * 32]);
#pragma unroll
  for (int i = 0; i < 4; ++i)
    load_lds16h(gB[i], &Bs[0][(w * 64 + i * 16) * 32]);
  __syncthreads();

  for (int t = 0; t < 16; ++t) {
    const int p = t & 1;
    // next-step DMA into the other buffers (in flight through MFMA phase)
    if (t < 15) {
#pragma unroll
      for (int j = 0; j < 2; ++j)
        load_lds16f(gA[j] + (t + 1) * 32, &As[p ^ 1][(w * 16 + j * 8) * 32]);
#pragma unroll
      for (int i = 0; i < 4; ++i)
        load_lds16h(gB[i] + (t + 1) * 32, &Bs[p ^ 1][(w * 64 + i * 16) * 32]);
    }
    // B fragments from LDS (swizzled: chunk lq of row r at slot lq^(r&3))
    half8 bf[8];
#pragma unroll
    for (int ni = 0; ni < 8; ++ni) {
      const int r = wu + ni * 16 + ln;
      bf[ni] = *(const half8*)&Bs[p][r * 32 + ((lq ^ (ln & 3)) * 8)];
    }
    // A fragments: 2x ds_read_b128 + cvt to half8
    half8 af[4];
#pragma unroll
    for (int mi = 0; mi < 4; ++mi) {
      const int r = wm + mi * 16 + ln;
      const float* row = &As[p][r * 32];
      const float4 lo = *(const float4*)(row + (((2 * lq) ^ (r & 7)) * 4));
      const float4 hi = *(const float4*)(row + (((2 * lq + 1) ^ (r & 7)) * 4));
      af[mi] = half8{(_Float16)lo.x, (_Float16)lo.y, (_Float16)lo.z,
                     (_Float16)lo.w, (_Float16)hi.x, (_Float16)hi.y,
                     (_Float16)hi.z, (_Float16)hi.w};
    }
#pragma unroll
    for (int mi = 0; mi < 4; ++mi)
#pragma unroll
      for (int ni = 0; ni < 8; ++ni)
        acc[mi][ni] = __builtin_amdgcn_mfma_f32_16x16x32_f16(
            af[mi], bf[ni], acc[mi][ni], 0, 0, 0);
    __syncthreads();  // buf[p] consumed; drains DMA(t+1) into buf[p^1]
  }

  // Epilogue: full row scores (each block owns its 128 rows exclusively).
  float pre[8], vv[8];
#pragma unroll
  for (int ni = 0; ni < 8; ++ni) {
    const int u = wu + ni * 16 + ln;
    pre[ni] = b1[u] + projq[b * U_ + u];
    vv[ni] = V[u];
  }
#pragma unroll
  for (int mi = 0; mi < 4; ++mi) {
#pragma unroll
    for (int r = 0; r < 4; ++r) {
      float t = 0.f;
#pragma unroll
      for (int ni = 0; ni < 8; ++ni)
        t += fast_tanh(acc[mi][ni][r] + pre[ni]) * vv[ni];
      t += __shfl_xor(t, 1);
      t += __shfl_xor(t, 2);
      t += __shfl_xor(t, 4);
      t += __shfl_xor(t, 8);
      if (ln == 0) red[w >> 1][wm + mi * 16 + lq * 4 + r] = t;
    }
  }
  __syncthreads();
  if (tid < 128)
    scores[m0 + tid] =
        red[0][tid] + red[1][tid] + red[2][tid] + red[3][tid];
}

// ---------------- fused softmax + context ----------------
// Grid (B, T/64). Every block recomputes batch-b softmax stats from scores
// (deterministic -> consistent across blocks), writes its 64-row weight
// slice, accumulates its context partial via atomics.
__global__ __launch_bounds__(256) void softmax_context_kernel(
    const float* __restrict__ scores, const float* __restrict__ values,
    float* __restrict__ weights, float* __restrict__ context) {
  const int b = blockIdx.x;
  const int t0 = blockIdx.y * 64;
  const int tid = threadIdx.x;

  // full-batch softmax stats
  float v[8];
  float mx = -INFINITY;
#pragma unroll
  for (int i = 0; i < 8; ++i) {
    v[i] = scores[b * T_ + i * 256 + tid];
    mx = fmaxf(mx, v[i]);
  }
#pragma unroll
  for (int off = 32; off > 0; off >>= 1) mx = fmaxf(mx, __shfl_down(mx, off));
  __shared__ float sm[4], ss[4];
  if ((tid & 63) == 0) sm[tid >> 6] = mx;
  __syncthreads();
  mx = fmaxf(fmaxf(sm[0], sm[1]), fmaxf(sm[2], sm[3]));
  float sum = 0.f;
#pragma unroll
  for (int i = 0; i < 8; ++i) sum += __expf(v[i] - mx);
#pragma unroll
  for (int off = 32; off > 0; off >>= 1) sum += __shfl_down(sum, off);
  if ((tid & 63) == 0) ss[tid >> 6] = sum;
  __syncthreads();
  const float inv = 1.f / (ss[0] + ss[1] + ss[2] + ss[3]);

  // weights for our 64 rows
  __shared__ float wsh[64];
  if (tid < 64) {
    const float ww = __expf(scores[b * T_ + t0 + tid] - mx) * inv;
    wsh[tid] = ww;
    weights[b * T_ + t0 + tid] = ww;
  }
  __syncthreads();

  // context partial
  const int g = tid >> 7;
  const int dx = tid & 127;
  __shared__ float4 part[128];
  float4 acc = make_float4(0.f, 0.f, 0.f, 0.f);
  const float4* vp = (const float4*)(values + (long)(b * T_ + t0 + g) * D_) + dx;
#pragma unroll 4
  for (int t = 0; t < 32; ++t) {
    const float4 x = vp[(long)(2 * t) * (D_ / 4)];
    const float ww = wsh[2 * t + g];
    acc.x += ww * x.x; acc.y += ww * x.y; acc.z += ww * x.z; acc.w += ww * x.w;
  }
  if (g == 0) part[dx] = acc;
  __syncthreads();
  if (g == 1) {
    const float4 p = part[dx];
    atomicAdd(&context[b * D_ + dx * 4 + 0], acc.x + p.x);
    atomicAdd(&context[b * D_ + dx * 4 + 1], acc.y + p.y);
    atomicAdd(&context[b * D_ + dx * 4 + 2], acc.z + p.z);
    atomicAdd(&context[b * D_ + dx * 4 + 3], acc.w + p.w);
  }
}

extern "C" void kernel_launch(void* const* d_in, const int* in_sizes, int n_in,
                              void* d_out, int out_size, void* d_ws, size_t ws_size,
                              hipStream_t stream) {
  const float* values = (const float*)d_in[0];
  const float* query = (const float*)d_in[1];
  const float* W1 = (const float*)d_in[2];
  const float* b1 = (const float*)d_in[3];
  const float* W2 = (const float*)d_in[4];
  const float* b2 = (const float*)d_in[5];
  const float* V = (const float*)d_in[6];
  // d_in[7] = bV: unused — softmax is shift-invariant.

  float* out = (float*)d_out;
  float* context = out;            // [32,512]
  float* weights = out + B_ * D_;  // [32,2048]
  float* projq = (float*)d_ws;                                // 64KB
  float* scores = projq + B_ * U_;                            // 256KB
  _Float16* w1t = (_Float16*)((char*)d_ws + 65536 + 262144);  // 512KB

  prep_fused<<<128, 256, 0, stream>>>(W1, query, W2, b2, w1t, projq, context);
  score_fused<<<M_ / 128, 512, 0, stream>>>(values, w1t, b1, projq, V, scores);
  softmax_context_kernel<<<dim3(B_, T_ / 64), 256, 0, stream>>>(
      scores, values, weights, context);
}